// Round 8
// baseline (8422.404 us; speedup 1.0000x reference)
//
#include <hip/hip_runtime.h>
#include <hip/hip_bf16.h>
#include <type_traits>

#define S_LEN 1024
#define BATCH 16
#define HID   384
#define DIN   768

// ---------------- LSTM scan configuration ----------------
// 8 groups = dir(2) x batch-quad(4); 32 member blocks per group (grid 256, 1/CU).
// The 4 batch-lanes (bb) of a wave read IDENTICAL Whh addresses -> the TA merges
// them into one L2 request: unique weight traffic 75 -> 18.9 MB/step (the r6
// bottleneck term). Exchange stays the r6-proven agent-scope IC path.
#define NGRP 8
#define GRP  32
#define BQ   4
#define UPB  12
#define NTHR 384

__device__ __forceinline__ float sigf(float x)     { return 1.f/(1.f + __expf(-x)); }
__device__ __forceinline__ float tanhfast(float x) { return 1.f - 2.f/(__expf(2.f*x) + 1.f); }

// ---------------- zero init: packed h-exchange {tag,val} buffer ----------------
// 8 groups x 2 slots x (4 batch x 384 units) x 8B = 196,608 B (24,576 u64).
// Re-zeroed every launch (harness poisons d_ws with 0xAA).
__global__ void zero_kernel(unsigned long long* hx)
{
    int i = blockIdx.x * blockDim.x + threadIdx.x;
    if (i < 24576) hx[i] = 0ull;
}

// ---------------- generic fp32 GEMM: C = act(A @ W^T + bias), OT output ----------------
// A [M,K] ldA, W [N,K], C [M,N] ldC.  BM=128 BN=64 BK=16, 256 threads.
template<int RELU, typename OT>
__global__ __launch_bounds__(256) void gemm_nt(
    const float* __restrict__ A, int ldA,
    const float* __restrict__ W,
    const float* __restrict__ bias,
    OT* __restrict__ C, int ldC,
    int M, int N, int K)
{
    __shared__ float As[16][132];
    __shared__ float Ws[16][68];
    const int tid = threadIdx.x;
    const int m0 = blockIdx.x * 128;
    const int n0 = blockIdx.y * 64;
    const int tm = (tid & 15) * 8;
    const int tn = (tid >> 4) * 4;

    float acc[8][4];
    #pragma unroll
    for (int i = 0; i < 8; i++)
        #pragma unroll
        for (int j = 0; j < 4; j++) acc[i][j] = 0.f;

    const int lrow = tid >> 2;
    const int lk   = (tid & 3) * 4;

    for (int k0 = 0; k0 < K; k0 += 16) {
        #pragma unroll
        for (int p = 0; p < 2; p++) {
            const int r = lrow + p * 64;
            const float4 av = *(const float4*)(A + (size_t)(m0 + r) * ldA + k0 + lk);
            As[lk+0][r] = av.x; As[lk+1][r] = av.y; As[lk+2][r] = av.z; As[lk+3][r] = av.w;
        }
        {
            float4 wv = make_float4(0.f, 0.f, 0.f, 0.f);
            if (n0 + lrow < N) wv = *(const float4*)(W + (size_t)(n0 + lrow) * K + k0 + lk);
            Ws[lk+0][lrow] = wv.x; Ws[lk+1][lrow] = wv.y; Ws[lk+2][lrow] = wv.z; Ws[lk+3][lrow] = wv.w;
        }
        __syncthreads();
        #pragma unroll
        for (int k = 0; k < 16; k++) {
            const float4 a0 = *(const float4*)&As[k][tm];
            const float4 a1 = *(const float4*)&As[k][tm + 4];
            const float4 bv = *(const float4*)&Ws[k][tn];
            const float am[8] = {a0.x, a0.y, a0.z, a0.w, a1.x, a1.y, a1.z, a1.w};
            const float bb[4] = {bv.x, bv.y, bv.z, bv.w};
            #pragma unroll
            for (int i = 0; i < 8; i++)
                #pragma unroll
                for (int j = 0; j < 4; j++) acc[i][j] += am[i] * bb[j];
        }
        __syncthreads();
    }

    #pragma unroll
    for (int i = 0; i < 8; i++) {
        const int m = m0 + tm + i;
        #pragma unroll
        for (int j = 0; j < 4; j++) {
            const int n = n0 + tn + j;
            if (n < N) {
                float v = acc[i][j] + bias[n];
                if (RELU) v = fmaxf(v, 0.f);
                if constexpr (std::is_same_v<OT, __hip_bfloat16>)
                    C[(size_t)m * ldC + n] = __float2bfloat16(v);
                else
                    C[(size_t)m * ldC + n] = v;
            }
        }
    }
}

// ---------------- persistent LSTM scan (one layer, both directions) ----------------
// grid 256 = 8 groups x 32 members; 384 threads; ~12.3 KB LDS.
// Member m owns units [m*12, m*12+12) for ALL 4 batches of its group.
// Thread (bb=tid&3, ss=(tid>>2)&7, rr=tid>>5): batch bb, unit rr, k-taps ss*4+32j.
// bb-lanes share weight addresses -> single merged L2 request (4x dedup).
// Exchange: packed 8B {tag(hi32),val(lo32)} agent-scope atomics; data IS the flag.
// Pend-mask poll + s_sleep backoff; hl double-buffered -> ONE barrier per step.
// 2-slot rotation safety: publish(step s)->slot s&1 tag s+1; stage(step s) polls
// slot (s-1)&1 for tag >= s. A fast block can only reach its step s+1 publish
// (overwriting slot (s-1)&1) after ALL owners published step s, which requires
// every block to have finished step-s staging (the last readers of that slot).
__global__ __launch_bounds__(NTHR) void lstm_scan(
    const __hip_bfloat16* __restrict__ gatesF, const __hip_bfloat16* __restrict__ gatesB,
    const float* __restrict__ WhhF,            const float* __restrict__ WhhB,
    float* __restrict__ out, unsigned long long* hx_all, int epoch)
{
    __shared__ float hl[2][BQ * HID];     // staged h_prev, 2 x 6 KB

    const int blk = blockIdx.x;
    const int g   = blk & 7;              // group
    const int m   = blk >> 3;             // member 0..31
    const int dir = g >> 2;
    const int b0  = (g & 3) * BQ;
    const int u0  = m * UPB;

    const __hip_bfloat16* gates = dir ? gatesB : gatesF;
    const float* Whh = dir ? WhhB : WhhF;
    unsigned long long* hx = hx_all + g * (2 * BQ * HID);   // [2 slots][4*384]

    const int tid = threadIdx.x;
    const int bb  = tid & 3;
    const int ss  = (tid >> 2) & 7;
    const int rr  = tid >> 5;             // 0..11
    const int ug  = u0 + rr;
    const bool owner = (ss == 0);

    // per-thread weight row pointers (4 gates), taps k = ss*4 + 32*j
    // (bb-lanes 0..3 hold identical pointers -> merged request)
    const float* wp0 = Whh + ((size_t)0 * HID + ug) * HID + ss * 4;
    const float* wp1 = Whh + ((size_t)1 * HID + ug) * HID + ss * 4;
    const float* wp2 = Whh + ((size_t)2 * HID + ug) * HID + ss * 4;
    const float* wp3 = Whh + ((size_t)3 * HID + ug) * HID + ss * 4;

    float c_state = 0.f;
    const unsigned tbase = (unsigned)epoch * 2048u;

    for (int t = 0; t < S_LEN; t++) {
        const int tt = dir ? (S_LEN - 1 - t) : t;

        // gate pre-activations (owners): issued BEFORE the poll so HBM latency
        // overlaps the wait
        float gx0 = 0.f, gx1 = 0.f, gx2 = 0.f, gx3 = 0.f;
        if (owner) {
            const __hip_bfloat16* gp =
                gates + ((size_t)((b0 + bb) * S_LEN + tt)) * (4 * HID) + ug;
            gx0 = __bfloat162float(gp[0]);
            gx1 = __bfloat162float(gp[HID]);
            gx2 = __bfloat162float(gp[2 * HID]);
            gx3 = __bfloat162float(gp[3 * HID]);
        }

        // ---- stage h_{t-1} into hl[t&1]: 4 packets/thread, pend-mask poll ----
        if (t == 0) {
            hl[0][tid] = 0.f; hl[0][tid + 384] = 0.f;
            hl[0][tid + 768] = 0.f; hl[0][tid + 1152] = 0.f;
        } else {
            const unsigned long long* src = hx + ((t + 1) & 1) * (BQ * HID);
            float* dst = hl[t & 1];
            const unsigned tgt = tbase + (unsigned)t;
            int pend = 15;
            long guard = 0;
            do {
                #pragma unroll
                for (int p = 0; p < 4; p++) {
                    if (pend & (1 << p)) {
                        const unsigned long long q = __hip_atomic_load(src + tid + 384 * p,
                            __ATOMIC_RELAXED, __HIP_MEMORY_SCOPE_AGENT);
                        if ((unsigned)(q >> 32) >= tgt) {
                            dst[tid + 384 * p] = __uint_as_float((unsigned)q);
                            pend &= ~(1 << p);
                        }
                    }
                }
                if (!pend) break;
                __builtin_amdgcn_s_sleep(1);   // backoff: IC hot-line congestion
            } while (++guard < (1L << 22));    // hang -> wrong answer, not deadlock
        }
        __syncthreads();   // the only barrier per step (hl double-buffered)

        // ---- 4 gate dots: weights stream from L2 (deduped over bb-lanes) ----
        const float* hrow = hl[t & 1] + bb * HID;
        float a0 = 0.f, a1 = 0.f, a2 = 0.f, a3 = 0.f;
        #pragma unroll
        for (int j = 0; j < 12; j++) {
            const float4 h4 = *(const float4*)(hrow + ss * 4 + 32 * j);
            const float4 w0 = *(const float4*)(wp0 + 32 * j);
            const float4 w1 = *(const float4*)(wp1 + 32 * j);
            const float4 w2 = *(const float4*)(wp2 + 32 * j);
            const float4 w3 = *(const float4*)(wp3 + 32 * j);
            a0 += h4.x*w0.x + h4.y*w0.y + h4.z*w0.z + h4.w*w0.w;
            a1 += h4.x*w1.x + h4.y*w1.y + h4.z*w1.z + h4.w*w1.w;
            a2 += h4.x*w2.x + h4.y*w2.y + h4.z*w2.z + h4.w*w2.w;
            a3 += h4.x*w3.x + h4.y*w3.y + h4.z*w3.z + h4.w*w3.w;
        }
        // reduce over ss (lane bits 2..4)
        a0 += __shfl_xor(a0, 4, 64); a0 += __shfl_xor(a0, 8, 64); a0 += __shfl_xor(a0, 16, 64);
        a1 += __shfl_xor(a1, 4, 64); a1 += __shfl_xor(a1, 8, 64); a1 += __shfl_xor(a1, 16, 64);
        a2 += __shfl_xor(a2, 4, 64); a2 += __shfl_xor(a2, 8, 64); a2 += __shfl_xor(a2, 16, 64);
        a3 += __shfl_xor(a3, 4, 64); a3 += __shfl_xor(a3, 8, 64); a3 += __shfl_xor(a3, 16, 64);

        if (owner) {
            const float ii = sigf(a0 + gx0);
            const float ff = sigf(a1 + gx1);
            const float gg = tanhfast(a2 + gx2);
            const float oo = sigf(a3 + gx3);
            c_state = ff * c_state + ii * gg;
            const float hn = oo * tanhfast(c_state);
            // publish packed {tag, h_t} — single 8B atomic, data IS the flag
            const unsigned long long pk =
                ((unsigned long long)(tbase + (unsigned)t + 1u) << 32) |
                (unsigned long long)__float_as_uint(hn);
            __hip_atomic_store(hx + (t & 1) * (BQ * HID) + bb * HID + ug, pk,
                               __ATOMIC_RELAXED, __HIP_MEMORY_SCOPE_AGENT);
            // plain store for downstream kernels (dispatch-end release covers it)
            out[((size_t)((b0 + bb) * S_LEN + tt)) * (2 * HID) + dir * HID + ug] = hn;
        }
        // no second barrier: step t+1 pollers write hl[(t+1)&1], disjoint from hl[t&1]
    }
}

// ---------------- windowed attention ----------------
// score_j = (h_i*w3 + w2) . h_j   (s1[i] and attn_b constant over j -> cancel in softmax)
__global__ __launch_bounds__(256) void attn_win(
    const float* __restrict__ hcat,   // [16][1024][768], h in cols 0..383
    const float* __restrict__ attnW,  // [1152] = w1|w2|w3
    float* __restrict__ ocat,         // same buffer, writes cols 384..767
    const int* __restrict__ wsz_p)
{
    __shared__ float q[HID];
    __shared__ float sc[96];
    __shared__ float p[96];
    const int blk = blockIdx.x;
    const int b = blk >> 10, i = blk & 1023;
    const int W = *wsz_p;
    const int jlo = max(i - W, 0), jhi = min(i + W, S_LEN - 1);
    const int nj = jhi - jlo + 1;
    const int tid = threadIdx.x;
    const float* hrow = hcat + (size_t)b * S_LEN * 768;

    if (tid < 96) {
        const float4 hv = *(const float4*)(hrow + (size_t)i * 768 + tid * 4);
        const float4 w3 = *(const float4*)(attnW + 768 + tid * 4);
        const float4 w2 = *(const float4*)(attnW + 384 + tid * 4);
        float4 r;
        r.x = hv.x*w3.x + w2.x; r.y = hv.y*w3.y + w2.y;
        r.z = hv.z*w3.z + w2.z; r.w = hv.w*w3.w + w2.w;
        *(float4*)(q + tid * 4) = r;
    }
    __syncthreads();

    const int wv = tid >> 6, lane = tid & 63;
    for (int jj = wv; jj < nj; jj += 4) {
        const float* hj = hrow + (size_t)(jlo + jj) * 768;
        float s = 0.f;
        #pragma unroll
        for (int c = 0; c < 6; c++) { const int d = lane + 64*c; s += q[d] * hj[d]; }
        #pragma unroll
        for (int st = 1; st < 64; st <<= 1) s += __shfl_xor(s, st, 64);
        if (lane == 0) sc[jj] = s;
    }
    __syncthreads();

    if (tid < 64) {
        float v1 = (tid < nj) ? sc[tid] : -3e38f;
        float v2 = (64 + tid < nj) ? sc[64 + tid] : -3e38f;
        float m = fmaxf(v1, v2);
        #pragma unroll
        for (int st = 1; st < 64; st <<= 1) m = fmaxf(m, __shfl_xor(m, st, 64));
        float e1 = (tid < nj) ? __expf(v1 - m) : 0.f;
        float e2 = (64 + tid < nj) ? __expf(v2 - m) : 0.f;
        float sum = e1 + e2;
        #pragma unroll
        for (int st = 1; st < 64; st <<= 1) sum += __shfl_xor(sum, st, 64);
        const float inv = 1.f / sum;
        if (tid < nj) p[tid] = e1 * inv;
        if (64 + tid < nj) p[64 + tid] = e2 * inv;
    }
    __syncthreads();

    if (tid < 192) {
        const int d = tid * 2;
        float s0 = 0.f, s1 = 0.f;
        for (int jj = 0; jj < nj; jj++) {
            const float* hj = hrow + (size_t)(jlo + jj) * 768 + d;
            const float pj = p[jj];
            s0 += pj * hj[0]; s1 += pj * hj[1];
        }
        float* o = ocat + (size_t)b * S_LEN * 768 + (size_t)i * 768 + 384 + d;
        o[0] = s0; o[1] = s1;
    }
}

// ---------------- final 96 -> 1 dot ----------------
__global__ __launch_bounds__(256) void final_dot(
    const float* __restrict__ y2, const float* __restrict__ W3,
    const float* __restrict__ b3, float* __restrict__ outp)
{
    __shared__ float w[96];
    const int tid = threadIdx.x;
    if (tid < 96) w[tid] = W3[tid];
    __syncthreads();
    const int r = blockIdx.x * 256 + tid;
    const float* row = y2 + (size_t)r * 96;
    float s = 0.f;
    #pragma unroll
    for (int c = 0; c < 24; c++) {
        const float4 v = ((const float4*)row)[c];
        s += v.x*w[c*4] + v.y*w[c*4+1] + v.z*w[c*4+2] + v.w*w[c*4+3];
    }
    outp[r] = s + b3[0];
}

// ---------------- launcher ----------------
extern "C" void kernel_launch(void* const* d_in, const int* in_sizes, int n_in,
                              void* d_out, int out_size, void* d_ws, size_t ws_size,
                              hipStream_t stream)
{
    const float* x        = (const float*)d_in[0];
    const float* l1_Wih_f = (const float*)d_in[1];
    const float* l1_Whh_f = (const float*)d_in[2];
    const float* l1_b_f   = (const float*)d_in[3];
    const float* l1_Wih_b = (const float*)d_in[4];
    const float* l1_Whh_b = (const float*)d_in[5];
    const float* l1_b_b   = (const float*)d_in[6];
    const float* l2_Wih_f = (const float*)d_in[7];
    const float* l2_Whh_f = (const float*)d_in[8];
    const float* l2_b_f   = (const float*)d_in[9];
    const float* l2_Wih_b = (const float*)d_in[10];
    const float* l2_Whh_b = (const float*)d_in[11];
    const float* l2_b_b   = (const float*)d_in[12];
    const float* fc1_W    = (const float*)d_in[13];
    const float* fc1_b    = (const float*)d_in[14];
    const float* attn_W   = (const float*)d_in[15];
    /* d_in[16] attn_b: cancels in softmax */
    const float* w1       = (const float*)d_in[17];
    const float* b1       = (const float*)d_in[18];
    const float* w2       = (const float*)d_in[19];
    const float* b2       = (const float*)d_in[20];
    const float* w3       = (const float*)d_in[21];
    const float* b3       = (const float*)d_in[22];
    const int*   wsz      = (const int*)d_in[23];

    // workspace layout (bytes), peak ~201.5 MiB
    char* wsb = (char*)d_ws;
    __hip_bfloat16*     gF  = (__hip_bfloat16*)(wsb);             // 50,331,648 B
    __hip_bfloat16*     gB  = (__hip_bfloat16*)(wsb +  50331648); // 50,331,648 B
    float*              seq = (float*)(wsb + 100663296);          // 50,331,648 B
    float*              hct = (float*)(wsb + 150994944);          // 50,331,648 B
    unsigned long long* hx  = (unsigned long long*)(wsb + 201326592); // 196,608 B
    float*              h2  = (float*)(wsb);                      // aliases gF (dead)
    float*              y1  = (float*)(wsb +  50331648);          // aliases gB (dead)
    float*              y2  = (float*)(wsb +  50331648 + 16777216);

    const int M = BATCH * S_LEN;   // 16384
    dim3 tb(256);

    // ---- layer 1 ----
    zero_kernel<<<dim3(96), tb, 0, stream>>>(hx);
    gemm_nt<0, __hip_bfloat16><<<dim3(M/128, 24), tb, 0, stream>>>(x, DIN, l1_Wih_f, l1_b_f, gF, 1536, M, 1536, DIN);
    gemm_nt<0, __hip_bfloat16><<<dim3(M/128, 24), tb, 0, stream>>>(x, DIN, l1_Wih_b, l1_b_b, gB, 1536, M, 1536, DIN);
    lstm_scan<<<dim3(256), dim3(NTHR), 0, stream>>>(gF, gB, l1_Whh_f, l1_Whh_b, seq, hx, 0);

    // ---- fc1 + windowed attention -> h_cat ----
    gemm_nt<0, float><<<dim3(M/128, 6), tb, 0, stream>>>(seq, 768, fc1_W, fc1_b, hct, 768, M, 384, 768);
    attn_win<<<dim3(M), tb, 0, stream>>>(hct, attn_W, hct, wsz);

    // ---- layer 2 ---- (epoch-tagged monotone tags: no re-zero needed)
    gemm_nt<0, __hip_bfloat16><<<dim3(M/128, 24), tb, 0, stream>>>(hct, 768, l2_Wih_f, l2_b_f, gF, 1536, M, 1536, 768);
    gemm_nt<0, __hip_bfloat16><<<dim3(M/128, 24), tb, 0, stream>>>(hct, 768, l2_Wih_b, l2_b_b, gB, 1536, M, 1536, 768);
    lstm_scan<<<dim3(256), dim3(NTHR), 0, stream>>>(gF, gB, l2_Whh_f, l2_Whh_b, seq, hx, 1);

    // ---- head: fc1 again, then MLP ----
    gemm_nt<0, float><<<dim3(M/128, 6), tb, 0, stream>>>(seq, 768, fc1_W, fc1_b, h2, 384, M, 384, 768);
    gemm_nt<1, float><<<dim3(M/128, 4), tb, 0, stream>>>(h2, 384, w1, b1, y1, 256, M, 256, 384);
    gemm_nt<1, float><<<dim3(M/128, 2), tb, 0, stream>>>(y1, 256, w2, b2, y2, 96, M, 96, 256);
    final_dot<<<dim3(M/256), tb, 0, stream>>>(y2, w3, b3, (float*)d_out);
}